// Round 1
// baseline (341.468 us; speedup 1.0000x reference)
//
#include <hip/hip_runtime.h>
#include <hip/hip_bf16.h>
#include <stdint.h>

#define MDIM 4096
#define NDIM 4096
#define KDIM 4096

typedef __attribute__((ext_vector_type(8))) __bf16 bf16x8;
typedef __attribute__((ext_vector_type(4))) float f32x4;

typedef const __attribute__((address_space(1))) void* gas_ptr;
typedef __attribute__((address_space(3))) void* las_ptr;

__device__ __forceinline__ void async_load16(const void* g, void* l) {
    // global -> LDS direct DMA, 16B per lane; LDS dest is wave-uniform base + lane*16
    __builtin_amdgcn_global_load_lds((gas_ptr)g, (las_ptr)l, 16, 0, 0);
}

__device__ __forceinline__ unsigned short f32_to_bf16_rne(float f) {
    union { float f; uint32_t u; } v; v.f = f;
    uint32_t u = v.u;
    return (unsigned short)((u + 0x7FFFu + ((u >> 16) & 1u)) >> 16);
}

// ---------------- conversion kernels ----------------

__global__ void cvt_x_bf16(const float* __restrict__ x, unsigned short* __restrict__ out) {
    int i = blockIdx.x * blockDim.x + threadIdx.x;   // one float4 per thread
    float4 v = ((const float4*)x)[i];
    ushort4 o;
    o.x = f32_to_bf16_rne(v.x);
    o.y = f32_to_bf16_rne(v.y);
    o.z = f32_to_bf16_rne(v.z);
    o.w = f32_to_bf16_rne(v.w);
    ((ushort4*)out)[i] = o;
}

// W: [K][N] fp32 -> WqT: [N][K] bf16 with values sign(W) in {-1,0,+1}
__global__ void sign_transpose(const float* __restrict__ W, unsigned short* __restrict__ WqT) {
    __shared__ unsigned short tile[64][65];   // tile[n][k], +1 pad
    const int n0 = blockIdx.x * 64;
    const int k0 = blockIdx.y * 64;
    const int tx = threadIdx.x;   // 0..63
    const int ty = threadIdx.y;   // 0..3
#pragma unroll
    for (int r = 0; r < 16; ++r) {
        int kk = ty * 16 + r;
        float w = W[(size_t)(k0 + kk) * NDIM + n0 + tx];
        unsigned short s = (w > 0.0f) ? 0x3F80u : ((w < 0.0f) ? 0xBF80u : 0u);
        tile[tx][kk] = s;   // transposed store into LDS
    }
    __syncthreads();
#pragma unroll
    for (int r = 0; r < 16; ++r) {
        int nn = ty * 16 + r;
        WqT[(size_t)(n0 + nn) * KDIM + k0 + tx] = tile[nn][tx];
    }
}

// ---------------- bf16 MFMA GEMM (m97 structure) ----------------
// C[M][N] = A[M][K](bf16) * B^T  where B stored as [N][K](bf16), + bias

__global__ __launch_bounds__(256) void gemm_bf16_bt(
        const unsigned short* __restrict__ A,    // [M][K] bf16
        const unsigned short* __restrict__ Bt,   // [N][K] bf16
        const float* __restrict__ bias,          // [N]
        float* __restrict__ C)                   // [M][N] fp32
{
    __shared__ __align__(16) unsigned short As[128 * 32];
    __shared__ __align__(16) unsigned short Bs[128 * 32];

    const int tid  = threadIdx.x;
    const int wave = tid >> 6;       // 0..3
    const int lane = tid & 63;
    const int wm = wave >> 1;        // wave row (0..1)
    const int wn = wave & 1;         // wave col (0..1)

    const int bm = blockIdx.y * 128;
    const int bn = blockIdx.x * 128;

    // --- staging addresses: each wave fills 2x (16 rows x 32 cols) chunks of As and Bs
    // lane i covers row base+(i>>2), col chunk (i&3)*8  (16B per lane, contiguous LDS)
    const int srow = wave * 32 + (lane >> 2);
    const int scol = (lane & 3) * 8;
    const unsigned short* a_g0 = A  + (size_t)(bm + srow) * KDIM + scol;
    const unsigned short* a_g1 = a_g0 + (size_t)16 * KDIM;
    const unsigned short* b_g0 = Bt + (size_t)(bn + srow) * KDIM + scol;
    const unsigned short* b_g1 = b_g0 + (size_t)16 * KDIM;
    unsigned short* as0 = &As[(wave * 32) * 32];
    unsigned short* as1 = &As[(wave * 32 + 16) * 32];
    unsigned short* bs0 = &Bs[(wave * 32) * 32];
    unsigned short* bs1 = &Bs[(wave * 32 + 16) * 32];

    // --- fragment read positions
    const int frow = lane & 15;          // m (A) / n (B)
    const int fk   = (lane >> 4) * 8;    // k offset within 32

    f32x4 acc[4][4] = {};

    for (int kt = 0; kt < KDIM; kt += 32) {
        async_load16(a_g0 + kt, as0);
        async_load16(a_g1 + kt, as1);
        async_load16(b_g0 + kt, bs0);
        async_load16(b_g1 + kt, bs1);
        __syncthreads();   // compiler emits vmcnt(0) drain before s_barrier

        bf16x8 af[4], bfr[4];
#pragma unroll
        for (int mi = 0; mi < 4; ++mi)
            af[mi] = *(const bf16x8*)&As[(wm * 64 + mi * 16 + frow) * 32 + fk];
#pragma unroll
        for (int ni = 0; ni < 4; ++ni)
            bfr[ni] = *(const bf16x8*)&Bs[(wn * 64 + ni * 16 + frow) * 32 + fk];

#pragma unroll
        for (int mi = 0; mi < 4; ++mi)
#pragma unroll
            for (int ni = 0; ni < 4; ++ni)
                acc[mi][ni] = __builtin_amdgcn_mfma_f32_16x16x32_bf16(
                    af[mi], bfr[ni], acc[mi][ni], 0, 0, 0);

        __syncthreads();   // protect LDS before next overwrite
    }

    // --- epilogue: C/D layout col=lane&15, row=(lane>>4)*4+reg  (m89/m91 verified)
#pragma unroll
    for (int ni = 0; ni < 4; ++ni) {
        int col = bn + wn * 64 + ni * 16 + frow;
        float bv = bias[col];
#pragma unroll
        for (int mi = 0; mi < 4; ++mi) {
            int row0 = bm + wm * 64 + mi * 16 + (lane >> 4) * 4;
#pragma unroll
            for (int r = 0; r < 4; ++r)
                C[(size_t)(row0 + r) * NDIM + col] = acc[mi][ni][r] + bv;
        }
    }
}

// ---------------- fallback (only if ws too small): fp32 vector GEMM ----------------

__global__ void fallback_gemm(const float* __restrict__ x, const float* __restrict__ W,
                              const float* __restrict__ b, float* __restrict__ out) {
    __shared__ float As[32][32];
    __shared__ float Bs[32][33];
    int tx = threadIdx.x, ty = threadIdx.y;
    int row = blockIdx.y * 32 + ty;
    int col = blockIdx.x * 32 + tx;
    float acc = 0.0f;
    for (int kt = 0; kt < KDIM; kt += 32) {
        As[ty][tx] = x[(size_t)row * KDIM + kt + tx];
        float w = W[(size_t)(kt + ty) * NDIM + col];
        Bs[ty][tx] = (w > 0.0f) ? 1.0f : ((w < 0.0f) ? -1.0f : 0.0f);
        __syncthreads();
#pragma unroll
        for (int k = 0; k < 32; ++k) acc += As[ty][k] * Bs[k][tx];
        __syncthreads();
    }
    out[(size_t)row * NDIM + col] = acc + b[col];
}

// ---------------- launcher ----------------

extern "C" void kernel_launch(void* const* d_in, const int* in_sizes, int n_in,
                              void* d_out, int out_size, void* d_ws, size_t ws_size,
                              hipStream_t stream) {
    const float* x = (const float*)d_in[0];
    const float* W = (const float*)d_in[1];
    const float* b = (const float*)d_in[2];
    float* out = (float*)d_out;

    const size_t need = (size_t)MDIM * KDIM * 2 + (size_t)KDIM * NDIM * 2;  // 64 MB
    if (ws_size >= need) {
        unsigned short* xbf = (unsigned short*)d_ws;
        unsigned short* wqT = xbf + (size_t)MDIM * KDIM;

        cvt_x_bf16<<<(MDIM * (size_t)KDIM / 4) / 256, 256, 0, stream>>>(x, xbf);
        sign_transpose<<<dim3(NDIM / 64, KDIM / 64), dim3(64, 4), 0, stream>>>(W, wqT);
        gemm_bf16_bt<<<dim3(NDIM / 128, MDIM / 128), 256, 0, stream>>>(xbf, wqT, b, out);
    } else {
        fallback_gemm<<<dim3(NDIM / 32, MDIM / 32), dim3(32, 32), 0, stream>>>(x, W, b, out);
    }
}

// Round 2
// 329.751 us; speedup vs baseline: 1.0355x; 1.0355x over previous
//
#include <hip/hip_runtime.h>
#include <hip/hip_bf16.h>
#include <stdint.h>

#define MDIM 4096
#define NDIM 4096
#define KDIM 4096

typedef __attribute__((ext_vector_type(8))) __bf16 bf16x8;
typedef __attribute__((ext_vector_type(4))) float f32x4;
typedef __attribute__((ext_vector_type(8))) unsigned short ushort8_t;

typedef const __attribute__((address_space(1))) void* gas_ptr;
typedef __attribute__((address_space(3))) void* las_ptr;

__device__ __forceinline__ void async_load16(const void* g, void* l) {
    // global -> LDS direct DMA, 16B per lane; LDS dest = wave-uniform base + lane*16
    __builtin_amdgcn_global_load_lds((gas_ptr)g, (las_ptr)l, 16, 0, 0);
}

__device__ __forceinline__ unsigned short f32_to_bf16_rne(float f) {
    union { float f; uint32_t u; } v; v.f = f;
    uint32_t u = v.u;
    return (unsigned short)((u + 0x7FFFu + ((u >> 16) & 1u)) >> 16);
}

// ---------------- fused prep kernel ----------------
// blocks [0, XBLKS): x fp32 -> bf16 (16B loads+stores, grid-stride)
// blocks [XBLKS, XBLKS+4096): W[k][n] fp32 -> sign -> bf16, transposed to WqT[n][k]

#define XBLKS 2048

__global__ void prep_kernel(const float* __restrict__ x, const float* __restrict__ W,
                            unsigned short* __restrict__ xbf, unsigned short* __restrict__ wqT) {
    if (blockIdx.x < XBLKS) {
        const int tot8 = MDIM * KDIM / 8;                  // 2097152 ushort8 groups
        int t = blockIdx.x * 256 + threadIdx.x;
        const int stride = XBLKS * 256;
        for (int i = t; i < tot8; i += stride) {
            float4 v0 = ((const float4*)x)[2 * i];
            float4 v1 = ((const float4*)x)[2 * i + 1];
            ushort8_t o;
            o[0] = f32_to_bf16_rne(v0.x); o[1] = f32_to_bf16_rne(v0.y);
            o[2] = f32_to_bf16_rne(v0.z); o[3] = f32_to_bf16_rne(v0.w);
            o[4] = f32_to_bf16_rne(v1.x); o[5] = f32_to_bf16_rne(v1.y);
            o[6] = f32_to_bf16_rne(v1.z); o[7] = f32_to_bf16_rne(v1.w);
            ((ushort8_t*)xbf)[i] = o;
        }
    } else {
        __shared__ unsigned short tile[64][65];            // [n][k], +1 pad (2-way = free)
        const int wb = blockIdx.x - XBLKS;                 // 0..4095
        const int n0 = (wb & 63) * 64;
        const int k0 = (wb >> 6) * 64;
        const int t = threadIdx.x;                         // 0..255
        // load: 4 rounds, one float4 (4 consecutive n) per thread per round
#pragma unroll
        for (int r = 0; r < 4; ++r) {
            int flat = r * 256 + t;                        // 0..1023
            int k    = flat >> 4;                          // 0..63
            int nch  = (flat & 15) * 4;
            float4 v = *(const float4*)&W[(size_t)(k0 + k) * NDIM + n0 + nch];
            tile[nch + 0][k] = (v.x > 0.f) ? 0x3F80u : ((v.x < 0.f) ? 0xBF80u : 0u);
            tile[nch + 1][k] = (v.y > 0.f) ? 0x3F80u : ((v.y < 0.f) ? 0xBF80u : 0u);
            tile[nch + 2][k] = (v.z > 0.f) ? 0x3F80u : ((v.z < 0.f) ? 0xBF80u : 0u);
            tile[nch + 3][k] = (v.w > 0.f) ? 0x3F80u : ((v.w < 0.f) ? 0xBF80u : 0u);
        }
        __syncthreads();
        // store: 2 rounds, each thread gathers 8 k's of one n -> one 16B store
#pragma unroll
        for (int r = 0; r < 2; ++r) {
            int flat = r * 256 + t;                        // 0..511
            int n    = flat >> 3;                          // 0..63
            int kch  = (flat & 7) * 8;
            ushort8_t o;
#pragma unroll
            for (int j = 0; j < 8; ++j) o[j] = tile[n][kch + j];
            *(ushort8_t*)&wqT[(size_t)(n0 + n) * KDIM + k0 + kch] = o;
        }
    }
}

// ---------------- bf16 MFMA GEMM: double-buffered, single barrier per K-iter ----------------
// C[M][N] = A[M][K](bf16) * Bt[N][K](bf16)^T + bias

__global__ __launch_bounds__(256) void gemm_bf16_bt(
        const unsigned short* __restrict__ A,
        const unsigned short* __restrict__ Bt,
        const float* __restrict__ bias,
        float* __restrict__ C)
{
    __shared__ __align__(16) unsigned short As0[128 * 32];
    __shared__ __align__(16) unsigned short Bs0[128 * 32];
    __shared__ __align__(16) unsigned short As1[128 * 32];
    __shared__ __align__(16) unsigned short Bs1[128 * 32];

    const int tid  = threadIdx.x;
    const int wave = tid >> 6;
    const int lane = tid & 63;
    const int wm = wave >> 1;
    const int wn = wave & 1;

    const int bm = blockIdx.y * 128;
    const int bn = blockIdx.x * 128;

    // staging: lane i -> row srow=(wave*32 + i>>2), col chunk (i&3)*8; 16B/lane
    const int srow = wave * 32 + (lane >> 2);
    const int scol = (lane & 3) * 8;
    const unsigned short* aG = A  + (size_t)(bm + srow) * KDIM + scol;
    const unsigned short* bG = Bt + (size_t)(bn + srow) * KDIM + scol;
    const int lofs = wave * 32 * 32;     // wave's chunk base in LDS (elements)

    const int frow = lane & 15;
    const int fk   = (lane >> 4) * 8;

    f32x4 acc[4][4] = {};

#define STAGE(AS, BS, KT)                                         \
    do {                                                          \
        async_load16(aG + (KT),              &AS[lofs]);          \
        async_load16(aG + (size_t)16*KDIM + (KT), &AS[lofs + 16*32]); \
        async_load16(bG + (KT),              &BS[lofs]);          \
        async_load16(bG + (size_t)16*KDIM + (KT), &BS[lofs + 16*32]); \
    } while (0)

#define COMPUTE(AS, BS)                                                        \
    do {                                                                       \
        bf16x8 af[4], bfr[4];                                                  \
        _Pragma("unroll")                                                      \
        for (int mi = 0; mi < 4; ++mi)                                         \
            af[mi] = *(const bf16x8*)&AS[(wm * 64 + mi * 16 + frow) * 32 + fk];\
        _Pragma("unroll")                                                      \
        for (int ni = 0; ni < 4; ++ni)                                         \
            bfr[ni] = *(const bf16x8*)&BS[(wn * 64 + ni * 16 + frow) * 32 + fk];\
        _Pragma("unroll")                                                      \
        for (int mi = 0; mi < 4; ++mi)                                         \
            _Pragma("unroll")                                                  \
            for (int ni = 0; ni < 4; ++ni)                                     \
                acc[mi][ni] = __builtin_amdgcn_mfma_f32_16x16x32_bf16(         \
                    af[mi], bfr[ni], acc[mi][ni], 0, 0, 0);                    \
    } while (0)

    STAGE(As0, Bs0, 0);
    __syncthreads();                      // buf0 ready (vmcnt(0) drain)

    for (int kt = 0; kt < KDIM; kt += 64) {
        // prefetch buf1 while computing buf0
        STAGE(As1, Bs1, kt + 32);
        COMPUTE(As0, Bs0);
        __syncthreads();                  // drains prefetch after compute covered latency

        if (kt + 64 < KDIM) STAGE(As0, Bs0, kt + 64);
        COMPUTE(As1, Bs1);
        __syncthreads();
    }

    // epilogue: C/D layout col=lane&15, row=(lane>>4)*4+reg (m89/m91 verified)
#pragma unroll
    for (int ni = 0; ni < 4; ++ni) {
        int col = bn + wn * 64 + ni * 16 + frow;
        float bv = bias[col];
#pragma unroll
        for (int mi = 0; mi < 4; ++mi) {
            int row0 = bm + wm * 64 + mi * 16 + (lane >> 4) * 4;
#pragma unroll
            for (int r = 0; r < 4; ++r)
                C[(size_t)(row0 + r) * NDIM + col] = acc[mi][ni][r] + bv;
        }
    }
#undef STAGE
#undef COMPUTE
}

// ---------------- fallback: fp32 vector GEMM (only if ws too small) ----------------

__global__ void fallback_gemm(const float* __restrict__ x, const float* __restrict__ W,
                              const float* __restrict__ b, float* __restrict__ out) {
    __shared__ float As[32][32];
    __shared__ float Bs[32][33];
    int tx = threadIdx.x, ty = threadIdx.y;
    int row = blockIdx.y * 32 + ty;
    int col = blockIdx.x * 32 + tx;
    float acc = 0.0f;
    for (int kt = 0; kt < KDIM; kt += 32) {
        As[ty][tx] = x[(size_t)row * KDIM + kt + tx];
        float w = W[(size_t)(kt + ty) * NDIM + col];
        Bs[ty][tx] = (w > 0.0f) ? 1.0f : ((w < 0.0f) ? -1.0f : 0.0f);
        __syncthreads();
#pragma unroll
        for (int k = 0; k < 32; ++k) acc += As[ty][k] * Bs[k][tx];
        __syncthreads();
    }
    out[(size_t)row * NDIM + col] = acc + b[col];
}

// ---------------- launcher ----------------

extern "C" void kernel_launch(void* const* d_in, const int* in_sizes, int n_in,
                              void* d_out, int out_size, void* d_ws, size_t ws_size,
                              hipStream_t stream) {
    const float* x = (const float*)d_in[0];
    const float* W = (const float*)d_in[1];
    const float* b = (const float*)d_in[2];
    float* out = (float*)d_out;

    const size_t need = (size_t)MDIM * KDIM * 2 + (size_t)KDIM * NDIM * 2;  // 64 MB
    if (ws_size >= need) {
        unsigned short* xbf = (unsigned short*)d_ws;
        unsigned short* wqT = xbf + (size_t)MDIM * KDIM;

        prep_kernel<<<XBLKS + (NDIM / 64) * (KDIM / 64), 256, 0, stream>>>(x, W, xbf, wqT);
        gemm_bf16_bt<<<dim3(NDIM / 128, MDIM / 128), 256, 0, stream>>>(xbf, wqT, b, out);
    } else {
        fallback_gemm<<<dim3(NDIM / 32, MDIM / 32), dim3(32, 32), 0, stream>>>(x, W, b, out);
    }
}

// Round 3
// 327.520 us; speedup vs baseline: 1.0426x; 1.0068x over previous
//
#include <hip/hip_runtime.h>
#include <hip/hip_bf16.h>
#include <stdint.h>

#define MDIM 4096
#define NDIM 4096
#define KDIM 4096

typedef __attribute__((ext_vector_type(8))) __bf16 bf16x8;
typedef __attribute__((ext_vector_type(4))) float f32x4;
typedef __attribute__((ext_vector_type(8))) unsigned short ushort8_t;

typedef const __attribute__((address_space(1))) void* gas_ptr;
typedef __attribute__((address_space(3))) void* las_ptr;

__device__ __forceinline__ void async_load16(const void* g, void* l) {
    // global -> LDS direct DMA, 16B per lane; LDS dest = wave-uniform base + lane*16
    __builtin_amdgcn_global_load_lds((gas_ptr)g, (las_ptr)l, 16, 0, 0);
}

__device__ __forceinline__ unsigned short f32_to_bf16_rne(float f) {
    union { float f; uint32_t u; } v; v.f = f;
    uint32_t u = v.u;
    return (unsigned short)((u + 0x7FFFu + ((u >> 16) & 1u)) >> 16);
}

// ---------------- fused prep kernel ----------------
// blocks [0, XBLKS): x fp32 -> bf16 (16B loads+stores, grid-stride)
// blocks [XBLKS, XBLKS+4096): W[k][n] fp32 -> sign -> bf16, transposed to WqT[n][k]

#define XBLKS 2048

__global__ void prep_kernel(const float* __restrict__ x, const float* __restrict__ W,
                            unsigned short* __restrict__ xbf, unsigned short* __restrict__ wqT) {
    if (blockIdx.x < XBLKS) {
        const int tot8 = MDIM * KDIM / 8;                  // 2097152 ushort8 groups
        int t = blockIdx.x * 256 + threadIdx.x;
        const int stride = XBLKS * 256;
        for (int i = t; i < tot8; i += stride) {
            float4 v0 = ((const float4*)x)[2 * i];
            float4 v1 = ((const float4*)x)[2 * i + 1];
            ushort8_t o;
            o[0] = f32_to_bf16_rne(v0.x); o[1] = f32_to_bf16_rne(v0.y);
            o[2] = f32_to_bf16_rne(v0.z); o[3] = f32_to_bf16_rne(v0.w);
            o[4] = f32_to_bf16_rne(v1.x); o[5] = f32_to_bf16_rne(v1.y);
            o[6] = f32_to_bf16_rne(v1.z); o[7] = f32_to_bf16_rne(v1.w);
            ((ushort8_t*)xbf)[i] = o;
        }
    } else {
        __shared__ unsigned short tile[64][65];            // [n][k], +1 pad
        const int wb = blockIdx.x - XBLKS;                 // 0..4095
        const int n0 = (wb & 63) * 64;
        const int k0 = (wb >> 6) * 64;
        const int t = threadIdx.x;                         // 0..255
#pragma unroll
        for (int r = 0; r < 4; ++r) {
            int flat = r * 256 + t;                        // 0..1023
            int k    = flat >> 4;                          // 0..63
            int nch  = (flat & 15) * 4;
            float4 v = *(const float4*)&W[(size_t)(k0 + k) * NDIM + n0 + nch];
            tile[nch + 0][k] = (v.x > 0.f) ? 0x3F80u : ((v.x < 0.f) ? 0xBF80u : 0u);
            tile[nch + 1][k] = (v.y > 0.f) ? 0x3F80u : ((v.y < 0.f) ? 0xBF80u : 0u);
            tile[nch + 2][k] = (v.z > 0.f) ? 0x3F80u : ((v.z < 0.f) ? 0xBF80u : 0u);
            tile[nch + 3][k] = (v.w > 0.f) ? 0x3F80u : ((v.w < 0.f) ? 0xBF80u : 0u);
        }
        __syncthreads();
#pragma unroll
        for (int r = 0; r < 2; ++r) {
            int flat = r * 256 + t;                        // 0..511
            int n    = flat >> 3;                          // 0..63
            int kch  = (flat & 7) * 8;
            ushort8_t o;
#pragma unroll
            for (int j = 0; j < 8; ++j) o[j] = tile[n][kch + j];
            *(ushort8_t*)&wqT[(size_t)(n0 + n) * KDIM + k0 + kch] = o;
        }
    }
}

// ---------------- bf16 MFMA GEMM: double-buffered + XOR-swizzled LDS ----------------
// LDS layout: row r (64B = 4 chunks of 16B), global chunk c stored at slot c^(r&3).
// Staging picks the matching global chunk per lane; fragment reads use q^(lane&3).
// This makes each 32-lane phase of ds_read_b128 cover all 8 bank groups: conflict-free.

__global__ __launch_bounds__(256) void gemm_bf16_bt(
        const unsigned short* __restrict__ A,
        const unsigned short* __restrict__ Bt,
        const float* __restrict__ bias,
        float* __restrict__ C)
{
    __shared__ __align__(16) unsigned short As0[128 * 32];
    __shared__ __align__(16) unsigned short Bs0[128 * 32];
    __shared__ __align__(16) unsigned short As1[128 * 32];
    __shared__ __align__(16) unsigned short Bs1[128 * 32];

    const int tid  = threadIdx.x;
    const int wave = tid >> 6;
    const int lane = tid & 63;
    const int wm = wave >> 1;
    const int wn = wave & 1;

    const int bm = blockIdx.y * 128;
    const int bn = blockIdx.x * 128;

    // staging: lane i -> LDS slot i (16B). LDS slot (row=i>>2, s=i&3) holds global
    // chunk c = s ^ (row&3). Row group per wave: rows wave*32 .. +15 (2nd DMA +16).
    const int srow = wave * 32 + (lane >> 2);
    const int scol = 8 * ((lane & 3) ^ ((lane >> 2) & 3));   // swizzled global chunk
    const unsigned short* aG = A  + (size_t)(bm + srow) * KDIM + scol;
    const unsigned short* bG = Bt + (size_t)(bn + srow) * KDIM + scol;
    const int lofs = wave * 32 * 32;     // wave's chunk base in LDS (elements)

    // fragment read: row = (base16 + frow), chunk q=(lane>>4) at slot q^(frow&3)
    const int frow = lane & 15;
    const int fks  = 8 * ((lane >> 4) ^ (lane & 3));         // swizzled chunk offset (elems)

    f32x4 acc[4][4] = {};

#define STAGE(AS, BS, KT)                                             \
    do {                                                              \
        async_load16(aG + (KT),                   &AS[lofs]);         \
        async_load16(aG + (size_t)16*KDIM + (KT), &AS[lofs + 16*32]); \
        async_load16(bG + (KT),                   &BS[lofs]);         \
        async_load16(bG + (size_t)16*KDIM + (KT), &BS[lofs + 16*32]); \
    } while (0)

#define COMPUTE(AS, BS)                                                         \
    do {                                                                        \
        bf16x8 af[4], bfr[4];                                                   \
        _Pragma("unroll")                                                       \
        for (int mi = 0; mi < 4; ++mi)                                          \
            af[mi] = *(const bf16x8*)&AS[(wm * 64 + mi * 16 + frow) * 32 + fks];\
        _Pragma("unroll")                                                       \
        for (int ni = 0; ni < 4; ++ni)                                          \
            bfr[ni] = *(const bf16x8*)&BS[(wn * 64 + ni * 16 + frow) * 32 + fks];\
        _Pragma("unroll")                                                       \
        for (int mi = 0; mi < 4; ++mi)                                          \
            _Pragma("unroll")                                                   \
            for (int ni = 0; ni < 4; ++ni)                                      \
                acc[mi][ni] = __builtin_amdgcn_mfma_f32_16x16x32_bf16(          \
                    af[mi], bfr[ni], acc[mi][ni], 0, 0, 0);                     \
    } while (0)

    STAGE(As0, Bs0, 0);
    __syncthreads();

    for (int kt = 0; kt < KDIM; kt += 64) {
        STAGE(As1, Bs1, kt + 32);       // prefetch buf1 while computing buf0
        COMPUTE(As0, Bs0);
        __syncthreads();

        if (kt + 64 < KDIM) STAGE(As0, Bs0, kt + 64);
        COMPUTE(As1, Bs1);
        __syncthreads();
    }

    // epilogue: C/D layout col=lane&15, row=(lane>>4)*4+reg (m89/m91 verified)
#pragma unroll
    for (int ni = 0; ni < 4; ++ni) {
        int col = bn + wn * 64 + ni * 16 + frow;
        float bv = bias[col];
#pragma unroll
        for (int mi = 0; mi < 4; ++mi) {
            int row0 = bm + wm * 64 + mi * 16 + (lane >> 4) * 4;
#pragma unroll
            for (int r = 0; r < 4; ++r)
                C[(size_t)(row0 + r) * NDIM + col] = acc[mi][ni][r] + bv;
        }
    }
#undef STAGE
#undef COMPUTE
}

// ---------------- fallback: fp32 vector GEMM (only if ws too small) ----------------

__global__ void fallback_gemm(const float* __restrict__ x, const float* __restrict__ W,
                              const float* __restrict__ b, float* __restrict__ out) {
    __shared__ float As[32][32];
    __shared__ float Bs[32][33];
    int tx = threadIdx.x, ty = threadIdx.y;
    int row = blockIdx.y * 32 + ty;
    int col = blockIdx.x * 32 + tx;
    float acc = 0.0f;
    for (int kt = 0; kt < KDIM; kt += 32) {
        As[ty][tx] = x[(size_t)row * KDIM + kt + tx];
        float w = W[(size_t)(kt + ty) * NDIM + col];
        Bs[ty][tx] = (w > 0.0f) ? 1.0f : ((w < 0.0f) ? -1.0f : 0.0f);
        __syncthreads();
#pragma unroll
        for (int k = 0; k < 32; ++k) acc += As[ty][k] * Bs[k][tx];
        __syncthreads();
    }
    out[(size_t)row * NDIM + col] = acc + b[col];
}

// ---------------- launcher ----------------

extern "C" void kernel_launch(void* const* d_in, const int* in_sizes, int n_in,
                              void* d_out, int out_size, void* d_ws, size_t ws_size,
                              hipStream_t stream) {
    const float* x = (const float*)d_in[0];
    const float* W = (const float*)d_in[1];
    const float* b = (const float*)d_in[2];
    float* out = (float*)d_out;

    const size_t need = (size_t)MDIM * KDIM * 2 + (size_t)KDIM * NDIM * 2;  // 64 MB
    if (ws_size >= need) {
        unsigned short* xbf = (unsigned short*)d_ws;
        unsigned short* wqT = xbf + (size_t)MDIM * KDIM;

        prep_kernel<<<XBLKS + (NDIM / 64) * (KDIM / 64), 256, 0, stream>>>(x, W, xbf, wqT);
        gemm_bf16_bt<<<dim3(NDIM / 128, MDIM / 128), 256, 0, stream>>>(xbf, wqT, b, out);
    } else {
        fallback_gemm<<<dim3(NDIM / 32, MDIM / 32), dim3(32, 32), 0, stream>>>(x, W, b, out);
    }
}

// Round 4
// 314.512 us; speedup vs baseline: 1.0857x; 1.0414x over previous
//
#include <hip/hip_runtime.h>
#include <hip/hip_bf16.h>
#include <stdint.h>

#define MDIM 4096
#define NDIM 4096
#define KDIM 4096

typedef __attribute__((ext_vector_type(8))) __bf16 bf16x8;
typedef __attribute__((ext_vector_type(4))) float f32x4;
typedef __attribute__((ext_vector_type(8))) unsigned short ushort8_t;

typedef const __attribute__((address_space(1))) void* gas_ptr;
typedef __attribute__((address_space(3))) void* las_ptr;

__device__ __forceinline__ void async_load16(const void* g, void* l) {
    // global -> LDS direct DMA, 16B per lane; LDS dest = wave-uniform base + lane*16
    __builtin_amdgcn_global_load_lds((gas_ptr)g, (las_ptr)l, 16, 0, 0);
}

__device__ __forceinline__ unsigned short f32_to_bf16_rne(float f) {
    union { float f; uint32_t u; } v; v.f = f;
    uint32_t u = v.u;
    return (unsigned short)((u + 0x7FFFu + ((u >> 16) & 1u)) >> 16);
}

// ---------------- fused prep kernel ----------------
// blocks [0, XBLKS): x fp32 -> bf16 (16B loads+stores, grid-stride)
// blocks [XBLKS, XBLKS+4096): W[k][n] fp32 -> sign -> bf16, transposed to WqT[n][k]

#define XBLKS 2048

__global__ void prep_kernel(const float* __restrict__ x, const float* __restrict__ W,
                            unsigned short* __restrict__ xbf, unsigned short* __restrict__ wqT) {
    if (blockIdx.x < XBLKS) {
        const int tot8 = MDIM * KDIM / 8;
        int t = blockIdx.x * 256 + threadIdx.x;
        const int stride = XBLKS * 256;
        for (int i = t; i < tot8; i += stride) {
            float4 v0 = ((const float4*)x)[2 * i];
            float4 v1 = ((const float4*)x)[2 * i + 1];
            ushort8_t o;
            o[0] = f32_to_bf16_rne(v0.x); o[1] = f32_to_bf16_rne(v0.y);
            o[2] = f32_to_bf16_rne(v0.z); o[3] = f32_to_bf16_rne(v0.w);
            o[4] = f32_to_bf16_rne(v1.x); o[5] = f32_to_bf16_rne(v1.y);
            o[6] = f32_to_bf16_rne(v1.z); o[7] = f32_to_bf16_rne(v1.w);
            ((ushort8_t*)xbf)[i] = o;
        }
    } else {
        __shared__ unsigned short tile[64][65];            // [n][k], +1 pad
        const int wb = blockIdx.x - XBLKS;
        const int n0 = (wb & 63) * 64;
        const int k0 = (wb >> 6) * 64;
        const int t = threadIdx.x;
#pragma unroll
        for (int r = 0; r < 4; ++r) {
            int flat = r * 256 + t;
            int k    = flat >> 4;
            int nch  = (flat & 15) * 4;
            float4 v = *(const float4*)&W[(size_t)(k0 + k) * NDIM + n0 + nch];
            tile[nch + 0][k] = (v.x > 0.f) ? 0x3F80u : ((v.x < 0.f) ? 0xBF80u : 0u);
            tile[nch + 1][k] = (v.y > 0.f) ? 0x3F80u : ((v.y < 0.f) ? 0xBF80u : 0u);
            tile[nch + 2][k] = (v.z > 0.f) ? 0x3F80u : ((v.z < 0.f) ? 0xBF80u : 0u);
            tile[nch + 3][k] = (v.w > 0.f) ? 0x3F80u : ((v.w < 0.f) ? 0xBF80u : 0u);
        }
        __syncthreads();
#pragma unroll
        for (int r = 0; r < 2; ++r) {
            int flat = r * 256 + t;
            int n    = flat >> 3;
            int kch  = (flat & 7) * 8;
            ushort8_t o;
#pragma unroll
            for (int j = 0; j < 8; ++j) o[j] = tile[n][kch + j];
            *(ushort8_t*)&wqT[(size_t)(n0 + n) * KDIM + k0 + kch] = o;
        }
    }
}

// ---------------- bf16 MFMA GEMM: dbuf, 4 blocks/CU (zero-tail grid) ----------------
// grid = 1024 = 256 CUs x 4 blocks -> exactly one full round IF <=128 regs/wave.
// Single LDS array so fragment reads are 2 lane-VGPRs + 16-bit immediates.
// buf layout (elements): buf b at b*4096; within buf, wave chunk at wave*1024.

__global__ __launch_bounds__(256, 4) void gemm_bf16_bt(
        const unsigned short* __restrict__ A,
        const unsigned short* __restrict__ Bt,
        const float* __restrict__ bias,
        float* __restrict__ C)
{
    // [0]=As0 [1]=Bs0 [2]=As1 [3]=Bs1
    __shared__ __align__(16) unsigned short lds[4][128 * 32];

    const int tid  = threadIdx.x;
    const int wave = tid >> 6;
    const int lane = tid & 63;
    const int wm = wave >> 1;
    const int wn = wave & 1;

    const int bm = blockIdx.y * 128;
    const int bn = blockIdx.x * 128;

    // staging: lane i -> row wave*32+(i>>2) (+16 for 2nd DMA), col chunk (i&3)*8
    const int srow = wave * 32 + (lane >> 2);
    const int scol = (lane & 3) * 8;
    const unsigned short* aG0 = A  + (size_t)(bm + srow) * KDIM + scol;
    const unsigned short* aG1 = aG0 + (size_t)16 * KDIM;
    const unsigned short* bG0 = Bt + (size_t)(bn + srow) * KDIM + scol;
    const unsigned short* bG1 = bG0 + (size_t)16 * KDIM;
    const int lofs = wave * 1024;        // wave chunk base within a buffer (elements)

    // fragment read element offsets within a buffer (lane-dependent, loop-invariant)
    const int frow = lane & 15;
    const int fk   = (lane >> 4) * 8;
    const int aoff = (wm * 64 + frow) * 32 + fk;   // + mi*512 imm
    const int boff = (wn * 64 + frow) * 32 + fk;   // + ni*512 imm

    f32x4 acc[4][4] = {};

#define STAGE(BUFA, BUFB, KT)                                    \
    do {                                                         \
        async_load16(aG0 + (KT), &lds[BUFA][lofs]);              \
        async_load16(aG1 + (KT), &lds[BUFA][lofs + 512]);        \
        async_load16(bG0 + (KT), &lds[BUFB][lofs]);              \
        async_load16(bG1 + (KT), &lds[BUFB][lofs + 512]);        \
    } while (0)

#define COMPUTE(BUFA, BUFB)                                                   \
    do {                                                                      \
        bf16x8 af[4], bfr[4];                                                 \
        _Pragma("unroll")                                                     \
        for (int mi = 0; mi < 4; ++mi)                                        \
            af[mi] = *(const bf16x8*)&lds[BUFA][aoff + mi * 512];             \
        _Pragma("unroll")                                                     \
        for (int ni = 0; ni < 4; ++ni)                                        \
            bfr[ni] = *(const bf16x8*)&lds[BUFB][boff + ni * 512];            \
        _Pragma("unroll")                                                     \
        for (int mi = 0; mi < 4; ++mi)                                        \
            _Pragma("unroll")                                                 \
            for (int ni = 0; ni < 4; ++ni)                                    \
                acc[mi][ni] = __builtin_amdgcn_mfma_f32_16x16x32_bf16(        \
                    af[mi], bfr[ni], acc[mi][ni], 0, 0, 0);                   \
    } while (0)

    STAGE(0, 1, 0);
    __syncthreads();

    for (int kt = 0; kt < KDIM; kt += 64) {
        STAGE(2, 3, kt + 32);                 // prefetch buf1 while computing buf0
        COMPUTE(0, 1);
        __syncthreads();

        // branchless wraparound on last iteration (redundant reload of tile 0;
        // kt is wave-uniform so this stays scalar arithmetic)
        int kt2 = (kt + 64) & (KDIM - 1);
        STAGE(0, 1, kt2);                     // prefetch buf0 while computing buf1
        COMPUTE(2, 3);
        __syncthreads();                      // also drains the final (unused) DMA
    }

    // epilogue: C/D layout col=lane&15, row=(lane>>4)*4+reg (m89/m91 verified)
#pragma unroll
    for (int ni = 0; ni < 4; ++ni) {
        int col = bn + wn * 64 + ni * 16 + frow;
        float bv = bias[col];
#pragma unroll
        for (int mi = 0; mi < 4; ++mi) {
            int row0 = bm + wm * 64 + mi * 16 + (lane >> 4) * 4;
#pragma unroll
            for (int r = 0; r < 4; ++r)
                C[(size_t)(row0 + r) * NDIM + col] = acc[mi][ni][r] + bv;
        }
    }
#undef STAGE
#undef COMPUTE
}

// ---------------- fallback: fp32 vector GEMM (only if ws too small) ----------------

__global__ void fallback_gemm(const float* __restrict__ x, const float* __restrict__ W,
                              const float* __restrict__ b, float* __restrict__ out) {
    __shared__ float As[32][32];
    __shared__ float Bs[32][33];
    int tx = threadIdx.x, ty = threadIdx.y;
    int row = blockIdx.y * 32 + ty;
    int col = blockIdx.x * 32 + tx;
    float acc = 0.0f;
    for (int kt = 0; kt < KDIM; kt += 32) {
        As[ty][tx] = x[(size_t)row * KDIM + kt + tx];
        float w = W[(size_t)(kt + ty) * NDIM + col];
        Bs[ty][tx] = (w > 0.0f) ? 1.0f : ((w < 0.0f) ? -1.0f : 0.0f);
        __syncthreads();
#pragma unroll
        for (int k = 0; k < 32; ++k) acc += As[ty][k] * Bs[k][tx];
        __syncthreads();
    }
    out[(size_t)row * NDIM + col] = acc + b[col];
}

// ---------------- launcher ----------------

extern "C" void kernel_launch(void* const* d_in, const int* in_sizes, int n_in,
                              void* d_out, int out_size, void* d_ws, size_t ws_size,
                              hipStream_t stream) {
    const float* x = (const float*)d_in[0];
    const float* W = (const float*)d_in[1];
    const float* b = (const float*)d_in[2];
    float* out = (float*)d_out;

    const size_t need = (size_t)MDIM * KDIM * 2 + (size_t)KDIM * NDIM * 2;  // 64 MB
    if (ws_size >= need) {
        unsigned short* xbf = (unsigned short*)d_ws;
        unsigned short* wqT = xbf + (size_t)MDIM * KDIM;

        prep_kernel<<<XBLKS + (NDIM / 64) * (KDIM / 64), 256, 0, stream>>>(x, W, xbf, wqT);
        gemm_bf16_bt<<<dim3(NDIM / 128, MDIM / 128), 256, 0, stream>>>(xbf, wqT, b, out);
    } else {
        fallback_gemm<<<dim3(NDIM / 32, MDIM / 32), dim3(32, 32), 0, stream>>>(x, W, b, out);
    }
}